// Round 8
// baseline (342.935 us; speedup 1.0000x reference)
//
#include <hip/hip_runtime.h>
#include <hip/hip_bf16.h>

typedef unsigned short ushort;
typedef unsigned int uint;
typedef __bf16 bf16x8 __attribute__((ext_vector_type(8)));
typedef float f32x4 __attribute__((ext_vector_type(4)));
typedef uint uint4v __attribute__((ext_vector_type(4)));
typedef uint uint2v __attribute__((ext_vector_type(2)));

#define CI 128
#define HIN 64
#define WIN 64
#define CO 256
#define HO 62
#define WO 62
#define NB 32
#define KTOT 1152            // 9 taps * 128 ci  (k = tap*128 + ci, repacked)
#define PIXIMG 3844          // 62*62
#define NPIX 123008          // 32*3844 = 128*961
#define XIMG 524288
#define NKT 18               // 1152/64 K-tiles

__device__ __forceinline__ ushort f2bf(float f) {
  uint u = __builtin_bit_cast(uint, f);
  u += 0x7fffu + ((u >> 16) & 1u);   // RNE
  return (ushort)(u >> 16);
}

// ---------------- prep: w[co][ci][3][3] fp32 -> w2[co][tap*128+ci] bf16 ----------------
__global__ void repack_w_kernel(const float* __restrict__ w, ushort* __restrict__ w2) {
  const int co = blockIdx.x;
  for (int idx = threadIdx.x; idx < KTOT; idx += 256) {
    const int t  = idx >> 7;
    const int ci = idx & 127;
    w2[co * KTOT + idx] = f2bf(w[(co * CI + ci) * 9 + t]);
  }
}

// ---------------- prep: x[n][ci][h][w] fp32 -> x2[n][h][w][ci] bf16 ----------------
#define XPAD 132
__global__ __launch_bounds__(256) void repack_x_kernel(const float* __restrict__ x,
                                                       ushort* __restrict__ x2) {
  __shared__ float t[WIN * XPAD];
  const int n = blockIdx.y;
  const int h = blockIdx.x;
  const int tid = threadIdx.x;
  const float* src = x + ((size_t)n * CI * HIN + h) * WIN;
  #pragma unroll
  for (int it = 0; it < 8; ++it) {
    const int idx = it * 256 + tid;
    const int ci  = idx >> 4;
    const int w4  = (idx & 15) * 4;
    const float4 v = *reinterpret_cast<const float4*>(src + (size_t)ci * (HIN * WIN) + w4);
    t[(w4 + 0) * XPAD + ci] = v.x;
    t[(w4 + 1) * XPAD + ci] = v.y;
    t[(w4 + 2) * XPAD + ci] = v.z;
    t[(w4 + 3) * XPAD + ci] = v.w;
  }
  __syncthreads();
  ushort* dst = x2 + ((size_t)(n * HIN + h) * WIN) * CI;
  #pragma unroll
  for (int it = 0; it < 4; ++it) {
    const int idx = it * 256 + tid;
    const int w   = idx >> 4;
    const int cig = idx & 15;
    const float* p = &t[w * XPAD + cig * 8];
    uint4v q;
    q[0] = (uint)f2bf(p[0]) | ((uint)f2bf(p[1]) << 16);
    q[1] = (uint)f2bf(p[2]) | ((uint)f2bf(p[3]) << 16);
    q[2] = (uint)f2bf(p[4]) | ((uint)f2bf(p[5]) << 16);
    q[3] = (uint)f2bf(p[6]) | ((uint)f2bf(p[7]) << 16);
    *reinterpret_cast<uint4v*>(dst + (size_t)w * CI + cig * 8) = q;
  }
}

// ================= main: 256x256x64 8-phase, next-phase read pipelining =================
// LDS: 2 dbuf x [s0 B-h0 | s1 A-h0 | s2 B-h1 | s3 A-h1], slot = 128rows x 64 bf16
// swizzle: phys_chunk = logical_chunk ^ (row&7), pre-swizzled global source.
// Per K-tile t (4 phases; reads consumed NEXT phase; gloads 2/phase; vmcnt(4) at p2,p4):
//   p1: rd A1(t)    st B1(t+1)->oth.s2            MFMA q00 = FA  x FB
//   p2: rd B1(t)    st A1(t+1)->oth.s3  vmcnt(4)  MFMA q10 = gaB x FB
//   p3: rd A0(t+1)  st B0(t+2)->cur.s0            MFMA q01 = FA  x gbB
//   p4: rd B0(t+1)  st A0(t+2)->cur.s1  vmcnt(4)  MFMA q11 = gaB x gbB
// vmcnt sits AFTER the stage and BEFORE the barrier (cross-wave propagation point).

#define GLOAD(SRC, DSTOFF) \
  __builtin_amdgcn_global_load_lds( \
      (const __attribute__((address_space(1))) uint*)(const void*)(SRC), \
      (__attribute__((address_space(3))) uint*)(void*)&lds[DSTOFF], 16, 0, 0)

#define STAGE_A(DB, SLOT, KT) do { \
  const int _ca = (KT) * 64; \
  GLOAD(w2 + aOff[(SLOT) >> 1][0] + _ca, (DB) + (SLOT) * 8192 + stgu);       \
  GLOAD(w2 + aOff[(SLOT) >> 1][1] + _ca, (DB) + (SLOT) * 8192 + stgu + 512); \
} while (0)

#define STAGE_B(DB, SLOT, KT) do { \
  const int _tp = (KT) >> 1; \
  const int _rr = (_tp * 11) >> 5; \
  const int _cb = (_rr * WIN + (_tp - _rr * 3)) * CI + ((KT) & 1) * 64; \
  GLOAD(x2 + bOff[(SLOT) >> 1][0] + _cb, (DB) + (SLOT) * 8192 + stgu);       \
  GLOAD(x2 + bOff[(SLOT) >> 1][1] + _cb, (DB) + (SLOT) * 8192 + stgu + 512); \
} while (0)

#define LOAD_A(F0, F1, LDB, SLOT) do { \
  _Pragma("unroll") for (int mf = 0; mf < 4; ++mf) { \
    F0[mf] = *reinterpret_cast<const bf16x8*>(&lds[(LDB) + (SLOT) * 8192 + arow + mf * 1024 + ck0]); \
    F1[mf] = *reinterpret_cast<const bf16x8*>(&lds[(LDB) + (SLOT) * 8192 + arow + mf * 1024 + ck1]); } \
} while (0)

#define LOAD_B(F0, F1, LDB, SLOT) do { \
  _Pragma("unroll") for (int nf = 0; nf < 2; ++nf) { \
    F0[nf] = *reinterpret_cast<const bf16x8*>(&lds[(LDB) + (SLOT) * 8192 + brow + nf * 1024 + ck0]); \
    F1[nf] = *reinterpret_cast<const bf16x8*>(&lds[(LDB) + (SLOT) * 8192 + brow + nf * 1024 + ck1]); } \
} while (0)

#define VMW4 asm volatile("s_waitcnt vmcnt(4)" ::: "memory")

#define MMAQ(MG, NG, A0, A1, B0, B1) do { \
  __builtin_amdgcn_s_barrier(); \
  __builtin_amdgcn_s_setprio(1); \
  _Pragma("unroll") for (int mf = 0; mf < 4; ++mf) \
    _Pragma("unroll") for (int nf = 0; nf < 2; ++nf) { \
      acc[(MG) * 4 + mf][(NG) * 2 + nf] = __builtin_amdgcn_mfma_f32_16x16x32_bf16( \
          A0[mf], B0[nf], acc[(MG) * 4 + mf][(NG) * 2 + nf], 0, 0, 0); \
      acc[(MG) * 4 + mf][(NG) * 2 + nf] = __builtin_amdgcn_mfma_f32_16x16x32_bf16( \
          A1[mf], B1[nf], acc[(MG) * 4 + mf][(NG) * 2 + nf], 0, 0, 0); } \
  __builtin_amdgcn_s_setprio(0); \
  __builtin_amdgcn_s_barrier(); \
} while (0)

// one K-tile: FA/FB = this tile's h0 fragments (already in regs); NFA/NFB get t+1's h0
#define TILE(LDB, FA0, FA1, FB0, FB1, NFA0, NFA1, NFB0, NFB1, TN1, TN2) do { \
  LOAD_A(gaB0, gaB1, (LDB), 3);           /* A1(t) */ \
  STAGE_B((LDB) ^ 32768, 2, (TN1)); \
  MMAQ(0, 0, FA0, FA1, FB0, FB1); \
  LOAD_B(gbB0, gbB1, (LDB), 2);           /* B1(t) */ \
  STAGE_A((LDB) ^ 32768, 3, (TN1)); \
  VMW4; \
  MMAQ(1, 0, gaB0, gaB1, FB0, FB1); \
  LOAD_A(NFA0, NFA1, (LDB) ^ 32768, 1);   /* A0(t+1) */ \
  STAGE_B((LDB), 0, (TN2)); \
  MMAQ(0, 1, FA0, FA1, gbB0, gbB1); \
  LOAD_B(NFB0, NFB1, (LDB) ^ 32768, 0);   /* B0(t+1) */ \
  STAGE_A((LDB), 1, (TN2)); \
  VMW4; \
  MMAQ(1, 1, gaB0, gaB1, gbB0, gbB1); \
} while (0)

__global__ __launch_bounds__(512, 2)
void conv_8ph_kernel(const ushort* __restrict__ x2, const ushort* __restrict__ w2,
                     float* __restrict__ out)
{
  __shared__ alignas(16) ushort lds[65536];   // 128 KiB

  const int tid  = threadIdx.x;
  const int lane = tid & 63;
  const int wid  = tid >> 6;    // 0..7
  const int wm   = wid >> 2;    // 0..1
  const int wn   = wid & 3;     // 0..3

  const int p0 = blockIdx.x * 256;   // 481 pixel tiles; last is half-valid

  // staging lane geometry (dest wave-uniform; HW adds lane*16B)
  const int lrow = lane >> 3;
  const int lc   = (lane & 7) ^ lrow;
  const int stgu = wid * 1024;

  int aOff[2][2];
  #pragma unroll
  for (int h = 0; h < 2; ++h)
    #pragma unroll
    for (int j = 0; j < 2; ++j)
      aOff[h][j] = (h * 128 + wid * 16 + j * 8 + lrow) * KTOT + lc * 8;

  int bOff[2][2];
  #pragma unroll
  for (int h = 0; h < 2; ++h)
    #pragma unroll
    for (int j = 0; j < 2; ++j) {
      int pglob = p0 + h * 128 + wid * 16 + j * 8 + lrow;
      pglob = pglob < NPIX ? pglob : (NPIX - 1);
      const int nimg = pglob / PIXIMG;
      const int prem = pglob - nimg * PIXIMG;
      const int oh   = prem / WO;
      const int ow   = prem - oh * WO;
      bOff[h][j] = ((nimg * HIN + oh) * WIN + ow) * CI + lc * 8;
    }

  const int arow = (wm * 64 + (lane & 15)) * 64;
  const int brow = (wn * 32 + (lane & 15)) * 64;
  const int ck0  = ((lane >> 4) ^ (lane & 7)) * 8;
  const int ck1  = ((4 + (lane >> 4)) ^ (lane & 7)) * 8;

  f32x4 acc[8][4];
  #pragma unroll
  for (int i = 0; i < 8; ++i)
    #pragma unroll
    for (int j = 0; j < 4; ++j)
      acc[i][j] = (f32x4){0.f, 0.f, 0.f, 0.f};

  bf16x8 fA0[4], fA1[4], nA0[4], nA1[4], gaB0[4], gaB1[4];
  bf16x8 fB0[2], fB1[2], nB0[2], nB1[2], gbB0[2], gbB1[2];

  // ---- prologue: t0 full + t1 B0,A0 (12 loads); vmcnt(4) -> t0 landed; preload h0 frags
  STAGE_B(0, 0, 0);
  STAGE_A(0, 1, 0);
  STAGE_B(0, 2, 0);
  STAGE_A(0, 3, 0);
  STAGE_B(32768, 0, 1);
  STAGE_A(32768, 1, 1);
  VMW4;
  __builtin_amdgcn_s_barrier();
  LOAD_A(fA0, fA1, 0, 1);   // A0(t0)
  LOAD_B(fB0, fB1, 0, 0);   // B0(t0)

  // ---- steady: tiles 0..15, ping-pong fragment names (2 tiles per iter) ----
  #pragma unroll 1
  for (int i = 0; i < 8; ++i) {
    const int t = 2 * i;
    TILE(0,     fA0, fA1, fB0, fB1, nA0, nA1, nB0, nB1, t + 1, t + 2);
    TILE(32768, nA0, nA1, nB0, nB1, fA0, fA1, fB0, fB1, t + 2, t + 3);
  }

  // ---- t=16 (cur buf 0; frags fA/fB): stage only t17's B1,A1; drain for t17 reads ----
  LOAD_A(gaB0, gaB1, 0, 3);
  STAGE_B(32768, 2, 17);
  MMAQ(0, 0, fA0, fA1, fB0, fB1);
  LOAD_B(gbB0, gbB1, 0, 2);
  STAGE_A(32768, 3, 17);
  VMW4;                      // t15-staged B0/A0(17) landed (for p3/p4 reads)
  MMAQ(1, 0, gaB0, gaB1, fB0, fB1);
  LOAD_A(nA0, nA1, 32768, 1);
  MMAQ(0, 1, fA0, fA1, gbB0, gbB1);
  LOAD_B(nB0, nB1, 32768, 0);
  asm volatile("s_waitcnt vmcnt(0)" ::: "memory");   // t16-staged B1/A1(17) landed
  MMAQ(1, 1, gaB0, gaB1, gbB0, gbB1);

  // ---- t=17 (buf 1; frags nA/nB): no stages, no vm waits ----
  LOAD_A(gaB0, gaB1, 32768, 3);
  MMAQ(0, 0, nA0, nA1, nB0, nB1);
  LOAD_B(gbB0, gbB1, 32768, 2);
  MMAQ(1, 0, gaB0, gaB1, nB0, nB1);
  MMAQ(0, 1, nA0, nA1, gbB0, gbB1);
  MMAQ(1, 1, gaB0, gaB1, gbB0, gbB1);

  // ---- epilogue ----
  #pragma unroll
  for (int ni = 0; ni < 4; ++ni) {
    const int pix = p0 + (ni >> 1) * 128 + wn * 32 + (ni & 1) * 16 + (lane & 15);
    if (pix < NPIX) {
      const int n2  = pix / PIXIMG;
      const int pr2 = pix - n2 * PIXIMG;
      float* ob = out + (size_t)n2 * (CO * PIXIMG) + pr2;
      #pragma unroll
      for (int mi = 0; mi < 8; ++mi) {
        const int cobase = (mi >> 2) * 128 + wm * 64 + (mi & 3) * 16 + ((lane >> 4) * 4);
        float* po = ob + (size_t)cobase * PIXIMG;
        #pragma unroll
        for (int r = 0; r < 4; ++r)
          po[(size_t)r * PIXIMG] = acc[mi][ni][r];
      }
    }
  }
}

// ---------------- fallback (tiny workspace): direct fp32 gather, reg-staged ----------------
__global__ __launch_bounds__(256, 3)
void conv_fallback_kernel(const float* __restrict__ x, const float* __restrict__ wt,
                          float* __restrict__ out)
{
  __shared__ alignas(16) ushort a_lds[128 * 64];
  __shared__ alignas(16) ushort b_lds[128 * 64];

  const int tid  = threadIdx.x;
  const int lane = tid & 63;
  const int wid  = tid >> 6;
  const int wrow = wid >> 1;
  const int wcol = wid & 1;
  const int co0 = blockIdx.x * 128;
  const int p0  = blockIdx.y * 128;

  const int pl    = tid & 127;
  const int kgsel = __builtin_amdgcn_readfirstlane(tid >> 7);
  const int pglob = p0 + pl;
  const int nimg  = pglob / PIXIMG;
  const int prem  = pglob - nimg * PIXIMG;
  const int oh    = prem / WO;
  const int ow    = prem - oh * WO;
  const int xpix  = nimg * XIMG + oh * WIN + ow;

  const int frow_a = wrow * 64 + (lane & 15);
  const int frow_b = wcol * 64 + (lane & 15);
  int aoff[2], boff[2];
  #pragma unroll
  for (int kk = 0; kk < 2; ++kk) {
    const int chk = (kk * 4 + (lane >> 4)) ^ (lane & 7);
    aoff[kk] = frow_a * 64 + chk * 8;
    boff[kk] = frow_b * 64 + chk * 8;
  }

  f32x4 acc[4][4];
  #pragma unroll
  for (int i = 0; i < 4; ++i)
    #pragma unroll
    for (int j = 0; j < 4; ++j)
      acc[i][j] = (f32x4){0.f, 0.f, 0.f, 0.f};

  for (int kt = 0; kt < NKT; ++kt) {
    const int k0 = kt * 64;
    if (kt) __syncthreads();

    #pragma unroll
    for (int it = 0; it < 4; ++it) {
      const int kg = kgsel + it * 2;
      uint pk[4];
      #pragma unroll
      for (int j = 0; j < 8; ++j) {
        const int k  = k0 + kg * 8 + j;
        const int ci = k / 9;
        const int rs = k - ci * 9;
        const int r  = rs / 3;
        const int s  = rs - r * 3;
        const ushort u = f2bf(x[xpix + ci * (HIN * WIN) + r * WIN + s]);
        if (j & 1) pk[j >> 1] |= ((uint)u) << 16;
        else       pk[j >> 1]  = (uint)u;
      }
      uint4v q = {pk[0], pk[1], pk[2], pk[3]};
      *reinterpret_cast<uint4v*>(&b_lds[pl * 64 + ((kg ^ (pl & 7)) * 8)]) = q;
    }

    #pragma unroll
    for (int i = 0; i < 8; ++i) {
      const int id  = i * 256 + tid;
      const int row = id >> 4;
      const int c4  = id & 15;
      const float4 v = *reinterpret_cast<const float4*>(
          wt + (size_t)(co0 + row) * KTOT + k0 + c4 * 4);
      uint2v q;
      q[0] = (uint)f2bf(v.x) | ((uint)f2bf(v.y) << 16);
      q[1] = (uint)f2bf(v.z) | ((uint)f2bf(v.w) << 16);
      *reinterpret_cast<uint2v*>(
          &a_lds[row * 64 + (((c4 >> 1) ^ (row & 7)) * 8) + (c4 & 1) * 4]) = q;
    }

    __syncthreads();

    #pragma unroll
    for (int kk = 0; kk < 2; ++kk) {
      bf16x8 af[4], bb[4];
      #pragma unroll
      for (int mi = 0; mi < 4; ++mi)
        af[mi] = *reinterpret_cast<const bf16x8*>(&a_lds[aoff[kk] + mi * (16 * 64)]);
      #pragma unroll
      for (int ni = 0; ni < 4; ++ni)
        bb[ni] = *reinterpret_cast<const bf16x8*>(&b_lds[boff[kk] + ni * (16 * 64)]);
      #pragma unroll
      for (int mi = 0; mi < 4; ++mi)
        #pragma unroll
        for (int ni = 0; ni < 4; ++ni)
          acc[mi][ni] = __builtin_amdgcn_mfma_f32_16x16x32_bf16(af[mi], bb[ni], acc[mi][ni], 0, 0, 0);
    }
  }

  #pragma unroll
  for (int ni = 0; ni < 4; ++ni) {
    const int pix = p0 + wcol * 64 + ni * 16 + (lane & 15);
    const int n2  = pix / PIXIMG;
    const int pr2 = pix - n2 * PIXIMG;
    float* ob = out + (size_t)n2 * (CO * PIXIMG) + pr2
                    + (size_t)(co0 + wrow * 64 + ((lane >> 4) * 4)) * PIXIMG;
    #pragma unroll
    for (int mi = 0; mi < 4; ++mi) {
      float* po = ob + (size_t)mi * (16 * PIXIMG);
      #pragma unroll
      for (int r = 0; r < 4; ++r)
        po[(size_t)r * PIXIMG] = acc[mi][ni][r];
    }
  }
}

extern "C" void kernel_launch(void* const* d_in, const int* in_sizes, int n_in,
                              void* d_out, int out_size, void* d_ws, size_t ws_size,
                              hipStream_t stream) {
  const float* x  = (const float*)d_in[0];
  const float* wt = (const float*)d_in[1];
  float* out = (float*)d_out;

  ushort* w2 = (ushort*)d_ws;
  ushort* x2 = (ushort*)((char*)d_ws + 589824);

  const size_t need = 589824 + (size_t)NB * XIMG * 2;   // ~34.1 MB

  if (ws_size >= need) {
    repack_w_kernel<<<dim3(CO), dim3(256), 0, stream>>>(wt, w2);
    repack_x_kernel<<<dim3(HIN, NB), dim3(256), 0, stream>>>(x, x2);
    conv_8ph_kernel<<<dim3(481), dim3(512), 0, stream>>>(x2, w2, out);
  } else {
    conv_fallback_kernel<<<dim3(CO / 128, NPIX / 128), dim3(256), 0, stream>>>(x, wt, out);
  }
}

// Round 9
// 209.377 us; speedup vs baseline: 1.6379x; 1.6379x over previous
//
#include <hip/hip_runtime.h>
#include <hip/hip_bf16.h>

typedef unsigned short ushort;
typedef unsigned int uint;
typedef __bf16 bf16x8 __attribute__((ext_vector_type(8)));
typedef float f32x4 __attribute__((ext_vector_type(4)));
typedef uint uint4v __attribute__((ext_vector_type(4)));
typedef uint uint2v __attribute__((ext_vector_type(2)));

#define CI 128
#define HIN 64
#define WIN 64
#define CO 256
#define HO 62
#define WO 62
#define NB 32
#define KTOT 1152            // 9 taps * 128 ci  (k = tap*128 + ci, repacked)
#define PIXIMG 3844          // 62*62
#define NPIX 123008          // 32*3844 = 128*961
#define XIMG 524288
#define NKT 18               // 1152/64 K-tiles

__device__ __forceinline__ ushort f2bf(float f) {
  uint u = __builtin_bit_cast(uint, f);
  u += 0x7fffu + ((u >> 16) & 1u);   // RNE
  return (ushort)(u >> 16);
}

// ---------------- prep: w[co][ci][3][3] fp32 -> w2[co][tap*128+ci] bf16 ----------------
__global__ void repack_w_kernel(const float* __restrict__ w, ushort* __restrict__ w2) {
  const int co = blockIdx.x;
  for (int idx = threadIdx.x; idx < KTOT; idx += 256) {
    const int t  = idx >> 7;
    const int ci = idx & 127;
    w2[co * KTOT + idx] = f2bf(w[(co * CI + ci) * 9 + t]);
  }
}

// ---------------- prep: x[n][ci][h][w] fp32 -> x2[n][h][w][ci] bf16 ----------------
#define XPAD 132
__global__ __launch_bounds__(256) void repack_x_kernel(const float* __restrict__ x,
                                                       ushort* __restrict__ x2) {
  __shared__ float t[WIN * XPAD];
  const int n = blockIdx.y;
  const int h = blockIdx.x;
  const int tid = threadIdx.x;
  const float* src = x + ((size_t)n * CI * HIN + h) * WIN;
  #pragma unroll
  for (int it = 0; it < 8; ++it) {
    const int idx = it * 256 + tid;
    const int ci  = idx >> 4;
    const int w4  = (idx & 15) * 4;
    const float4 v = *reinterpret_cast<const float4*>(src + (size_t)ci * (HIN * WIN) + w4);
    t[(w4 + 0) * XPAD + ci] = v.x;
    t[(w4 + 1) * XPAD + ci] = v.y;
    t[(w4 + 2) * XPAD + ci] = v.z;
    t[(w4 + 3) * XPAD + ci] = v.w;
  }
  __syncthreads();
  ushort* dst = x2 + ((size_t)(n * HIN + h) * WIN) * CI;
  #pragma unroll
  for (int it = 0; it < 4; ++it) {
    const int idx = it * 256 + tid;
    const int w   = idx >> 4;
    const int cig = idx & 15;
    const float* p = &t[w * XPAD + cig * 8];
    uint4v q;
    q[0] = (uint)f2bf(p[0]) | ((uint)f2bf(p[1]) << 16);
    q[1] = (uint)f2bf(p[2]) | ((uint)f2bf(p[3]) << 16);
    q[2] = (uint)f2bf(p[4]) | ((uint)f2bf(p[5]) << 16);
    q[3] = (uint)f2bf(p[6]) | ((uint)f2bf(p[7]) << 16);
    *reinterpret_cast<uint4v*>(dst + (size_t)w * CI + cig * 8) = q;
  }
}

// ============ main: 256x256x64 8-phase, next-phase reads, 96-VGPR frag budget ============
// LDS: 2 dbuf x [s0 B-h0 | s1 A-h0 | s2 B-h1 | s3 A-h1], slot = 128rows x 64 bf16 (h = ROW half)
// swizzle: phys_chunk = logical_chunk ^ (row&7), pre-swizzled global source.
// Tile t (cur=C, oth=O; quadrant q(MG,NG) = A-hMG x B-hNG):
//   p1: rd C.s2->b1   st O.s2=B1(t+1)            q00(a0,b0)
//   p2: rd C.s3->a1   st O.s3=A1(t+1)  vmcnt(4)  q01(a0,b1)   [a0 dead after]
//   p3: rd O.s1->a0'  st C.s0=B0(t+2)            q10(a1,b0)   [b0 dead after]
//   p4: rd O.s0->b0'  st C.s1=A0(t+2)  vmcnt(4)  q11(a1,b1)
// vmcnt(4) FIFO-checked: p2's retires t+1's h0 (staged p3/p4 of t-1) before p3/p4 reads;
// p4's retires t+1's h1 (staged p1/p2 of t) before next tile's p1/p2 reads.
// WAR: every staged slot's last reader consumed >=2 barriers before the stage issues.

#define GLOAD(SRC, DSTOFF) \
  __builtin_amdgcn_global_load_lds( \
      (const __attribute__((address_space(1))) uint*)(const void*)(SRC), \
      (__attribute__((address_space(3))) uint*)(void*)&lds[DSTOFF], 16, 0, 0)

#define STAGE_A(DB, SLOT, KT) do { \
  const int _ca = (KT) * 64; \
  GLOAD(w2 + aOff[(SLOT) >> 1][0] + _ca, (DB) + (SLOT) * 8192 + stgu);       \
  GLOAD(w2 + aOff[(SLOT) >> 1][1] + _ca, (DB) + (SLOT) * 8192 + stgu + 512); \
} while (0)

#define STAGE_B(DB, SLOT, KT) do { \
  const int _tp = (KT) >> 1; \
  const int _rr = (_tp * 11) >> 5; \
  const int _cb = (_rr * WIN + (_tp - _rr * 3)) * CI + ((KT) & 1) * 64; \
  GLOAD(x2 + bOff[(SLOT) >> 1][0] + _cb, (DB) + (SLOT) * 8192 + stgu);       \
  GLOAD(x2 + bOff[(SLOT) >> 1][1] + _cb, (DB) + (SLOT) * 8192 + stgu + 512); \
} while (0)

#define LOAD_A(F0, F1, LDB, SLOT) do { \
  _Pragma("unroll") for (int mf = 0; mf < 4; ++mf) { \
    F0[mf] = *reinterpret_cast<const bf16x8*>(&lds[(LDB) + (SLOT) * 8192 + arow + mf * 1024 + ck0]); \
    F1[mf] = *reinterpret_cast<const bf16x8*>(&lds[(LDB) + (SLOT) * 8192 + arow + mf * 1024 + ck1]); } \
} while (0)

#define LOAD_B(F0, F1, LDB, SLOT) do { \
  _Pragma("unroll") for (int nf = 0; nf < 2; ++nf) { \
    F0[nf] = *reinterpret_cast<const bf16x8*>(&lds[(LDB) + (SLOT) * 8192 + brow + nf * 1024 + ck0]); \
    F1[nf] = *reinterpret_cast<const bf16x8*>(&lds[(LDB) + (SLOT) * 8192 + brow + nf * 1024 + ck1]); } \
} while (0)

#define VMW4 asm volatile("s_waitcnt vmcnt(4)" ::: "memory")

#define MMAQ(MG, NG, A0, A1, B0, B1) do { \
  __builtin_amdgcn_s_barrier(); \
  __builtin_amdgcn_s_setprio(1); \
  _Pragma("unroll") for (int mf = 0; mf < 4; ++mf) \
    _Pragma("unroll") for (int nf = 0; nf < 2; ++nf) { \
      acc[(MG) * 4 + mf][(NG) * 2 + nf] = __builtin_amdgcn_mfma_f32_16x16x32_bf16( \
          A0[mf], B0[nf], acc[(MG) * 4 + mf][(NG) * 2 + nf], 0, 0, 0); \
      acc[(MG) * 4 + mf][(NG) * 2 + nf] = __builtin_amdgcn_mfma_f32_16x16x32_bf16( \
          A1[mf], B1[nf], acc[(MG) * 4 + mf][(NG) * 2 + nf], 0, 0, 0); } \
  __builtin_amdgcn_s_setprio(0); \
  __builtin_amdgcn_s_barrier(); \
} while (0)

#define TILE(LDB, T) do { \
  LOAD_B(b1k0, b1k1, (LDB), 2); \
  STAGE_B((LDB) ^ 32768, 2, (T) + 1); \
  MMAQ(0, 0, a0k0, a0k1, b0k0, b0k1); \
  LOAD_A(a1k0, a1k1, (LDB), 3); \
  STAGE_A((LDB) ^ 32768, 3, (T) + 1); \
  VMW4; \
  MMAQ(0, 1, a0k0, a0k1, b1k0, b1k1); \
  LOAD_A(a0k0, a0k1, (LDB) ^ 32768, 1); \
  STAGE_B((LDB), 0, (T) + 2); \
  MMAQ(1, 0, a1k0, a1k1, b0k0, b0k1); \
  LOAD_B(b0k0, b0k1, (LDB) ^ 32768, 0); \
  STAGE_A((LDB), 1, (T) + 2); \
  VMW4; \
  MMAQ(1, 1, a1k0, a1k1, b1k0, b1k1); \
} while (0)

__global__ __launch_bounds__(512, 2)
void conv_8ph_kernel(const ushort* __restrict__ x2, const ushort* __restrict__ w2,
                     float* __restrict__ out)
{
  __shared__ alignas(16) ushort lds[65536];   // 128 KiB

  const int tid  = threadIdx.x;
  const int lane = tid & 63;
  const int wid  = tid >> 6;    // 0..7
  const int wm   = wid >> 2;    // 0..1
  const int wn   = wid & 3;     // 0..3

  const int p0 = blockIdx.x * 256;   // 481 pixel tiles; last is half-valid

  // staging lane geometry (dest wave-uniform; HW adds lane*16B)
  const int lrow = lane >> 3;
  const int lc   = (lane & 7) ^ lrow;
  const int stgu = wid * 1024;

  int aOff[2][2];
  #pragma unroll
  for (int h = 0; h < 2; ++h)
    #pragma unroll
    for (int j = 0; j < 2; ++j)
      aOff[h][j] = (h * 128 + wid * 16 + j * 8 + lrow) * KTOT + lc * 8;

  int bOff[2][2];
  #pragma unroll
  for (int h = 0; h < 2; ++h)
    #pragma unroll
    for (int j = 0; j < 2; ++j) {
      int pglob = p0 + h * 128 + wid * 16 + j * 8 + lrow;
      pglob = pglob < NPIX ? pglob : (NPIX - 1);
      const int nimg = pglob / PIXIMG;
      const int prem = pglob - nimg * PIXIMG;
      const int oh   = prem / WO;
      const int ow   = prem - oh * WO;
      bOff[h][j] = ((nimg * HIN + oh) * WIN + ow) * CI + lc * 8;
    }

  const int arow = (wm * 64 + (lane & 15)) * 64;
  const int brow = (wn * 32 + (lane & 15)) * 64;
  const int ck0  = ((lane >> 4) ^ (lane & 7)) * 8;
  const int ck1  = ((4 + (lane >> 4)) ^ (lane & 7)) * 8;

  f32x4 acc[8][4];
  #pragma unroll
  for (int i = 0; i < 8; ++i)
    #pragma unroll
    for (int j = 0; j < 4; ++j)
      acc[i][j] = (f32x4){0.f, 0.f, 0.f, 0.f};

  // fragment registers: 96 VGPR total (R7-proven budget, no spill)
  bf16x8 a0k0[4], a0k1[4], a1k0[4], a1k1[4];
  bf16x8 b0k0[2], b0k1[2], b1k0[2], b1k1[2];

  // ---- prologue: t0 full + t1's h0 (12 gloads); vmcnt(4) -> t0 landed; preload a0/b0 ----
  STAGE_B(0, 0, 0);
  STAGE_A(0, 1, 0);
  STAGE_B(0, 2, 0);
  STAGE_A(0, 3, 0);
  STAGE_B(32768, 0, 1);
  STAGE_A(32768, 1, 1);
  VMW4;
  __builtin_amdgcn_s_barrier();
  LOAD_A(a0k0, a0k1, 0, 1);   // A0(t0)
  LOAD_B(b0k0, b0k1, 0, 0);   // B0(t0)

  // ---- steady: tiles 0..15 (2 per iter, ping-pong buffers) ----
  #pragma unroll 1
  for (int i = 0; i < 8; ++i) {
    const int t = 2 * i;
    TILE(0,     t);
    TILE(32768, t + 1);
  }

  // ---- t=16 (cur=buf0): stage only t17's h1 at p1/p2; drain at p4 ----
  LOAD_B(b1k0, b1k1, 0, 2);
  STAGE_B(32768, 2, 17);
  MMAQ(0, 0, a0k0, a0k1, b0k0, b0k1);
  LOAD_A(a1k0, a1k1, 0, 3);
  STAGE_A(32768, 3, 17);
  VMW4;                               // t17's h0 (staged p3/p4 of t15) landed
  MMAQ(0, 1, a0k0, a0k1, b1k0, b1k1);
  LOAD_A(a0k0, a0k1, 32768, 1);       // A0(17)
  MMAQ(1, 0, a1k0, a1k1, b0k0, b0k1);
  LOAD_B(b0k0, b0k1, 32768, 0);       // B0(17)
  asm volatile("s_waitcnt vmcnt(0)" ::: "memory");   // t17's h1 landed
  MMAQ(1, 1, a1k0, a1k1, b1k0, b1k1);

  // ---- t=17 (cur=buf1): no stages, no vm waits ----
  LOAD_B(b1k0, b1k1, 32768, 2);
  MMAQ(0, 0, a0k0, a0k1, b0k0, b0k1);
  LOAD_A(a1k0, a1k1, 32768, 3);
  MMAQ(0, 1, a0k0, a0k1, b1k0, b1k1);
  MMAQ(1, 0, a1k0, a1k1, b0k0, b0k1);
  MMAQ(1, 1, a1k0, a1k1, b1k0, b1k1);

  // ---- epilogue ----
  #pragma unroll
  for (int ni = 0; ni < 4; ++ni) {
    const int pix = p0 + (ni >> 1) * 128 + wn * 32 + (ni & 1) * 16 + (lane & 15);
    if (pix < NPIX) {
      const int n2  = pix / PIXIMG;
      const int pr2 = pix - n2 * PIXIMG;
      float* ob = out + (size_t)n2 * (CO * PIXIMG) + pr2;
      #pragma unroll
      for (int mi = 0; mi < 8; ++mi) {
        const int cobase = (mi >> 2) * 128 + wm * 64 + (mi & 3) * 16 + ((lane >> 4) * 4);
        float* po = ob + (size_t)cobase * PIXIMG;
        #pragma unroll
        for (int r = 0; r < 4; ++r)
          po[(size_t)r * PIXIMG] = acc[mi][ni][r];
      }
    }
  }
}

// ---------------- fallback (tiny workspace): direct fp32 gather, reg-staged ----------------
__global__ __launch_bounds__(256, 3)
void conv_fallback_kernel(const float* __restrict__ x, const float* __restrict__ wt,
                          float* __restrict__ out)
{
  __shared__ alignas(16) ushort a_lds[128 * 64];
  __shared__ alignas(16) ushort b_lds[128 * 64];

  const int tid  = threadIdx.x;
  const int lane = tid & 63;
  const int wid  = tid >> 6;
  const int wrow = wid >> 1;
  const int wcol = wid & 1;
  const int co0 = blockIdx.x * 128;
  const int p0  = blockIdx.y * 128;

  const int pl    = tid & 127;
  const int kgsel = __builtin_amdgcn_readfirstlane(tid >> 7);
  const int pglob = p0 + pl;
  const int nimg  = pglob / PIXIMG;
  const int prem  = pglob - nimg * PIXIMG;
  const int oh    = prem / WO;
  const int ow    = prem - oh * WO;
  const int xpix  = nimg * XIMG + oh * WIN + ow;

  const int frow_a = wrow * 64 + (lane & 15);
  const int frow_b = wcol * 64 + (lane & 15);
  int aoff[2], boff[2];
  #pragma unroll
  for (int kk = 0; kk < 2; ++kk) {
    const int chk = (kk * 4 + (lane >> 4)) ^ (lane & 7);
    aoff[kk] = frow_a * 64 + chk * 8;
    boff[kk] = frow_b * 64 + chk * 8;
  }

  f32x4 acc[4][4];
  #pragma unroll
  for (int i = 0; i < 4; ++i)
    #pragma unroll
    for (int j = 0; j < 4; ++j)
      acc[i][j] = (f32x4){0.f, 0.f, 0.f, 0.f};

  for (int kt = 0; kt < NKT; ++kt) {
    const int k0 = kt * 64;
    if (kt) __syncthreads();

    #pragma unroll
    for (int it = 0; it < 4; ++it) {
      const int kg = kgsel + it * 2;
      uint pk[4];
      #pragma unroll
      for (int j = 0; j < 8; ++j) {
        const int k  = k0 + kg * 8 + j;
        const int ci = k / 9;
        const int rs = k - ci * 9;
        const int r  = rs / 3;
        const int s  = rs - r * 3;
        const ushort u = f2bf(x[xpix + ci * (HIN * WIN) + r * WIN + s]);
        if (j & 1) pk[j >> 1] |= ((uint)u) << 16;
        else       pk[j >> 1]  = (uint)u;
      }
      uint4v q = {pk[0], pk[1], pk[2], pk[3]};
      *reinterpret_cast<uint4v*>(&b_lds[pl * 64 + ((kg ^ (pl & 7)) * 8)]) = q;
    }

    #pragma unroll
    for (int i = 0; i < 8; ++i) {
      const int id  = i * 256 + tid;
      const int row = id >> 4;
      const int c4  = id & 15;
      const float4 v = *reinterpret_cast<const float4*>(
          wt + (size_t)(co0 + row) * KTOT + k0 + c4 * 4);
      uint2v q;
      q[0] = (uint)f2bf(v.x) | ((uint)f2bf(v.y) << 16);
      q[1] = (uint)f2bf(v.z) | ((uint)f2bf(v.w) << 16);
      *reinterpret_cast<uint2v*>(
          &a_lds[row * 64 + (((c4 >> 1) ^ (row & 7)) * 8) + (c4 & 1) * 4]) = q;
    }

    __syncthreads();

    #pragma unroll
    for (int kk = 0; kk < 2; ++kk) {
      bf16x8 af[4], bb[4];
      #pragma unroll
      for (int mi = 0; mi < 4; ++mi)
        af[mi] = *reinterpret_cast<const bf16x8*>(&a_lds[aoff[kk] + mi * (16 * 64)]);
      #pragma unroll
      for (int ni = 0; ni < 4; ++ni)
        bb[ni] = *reinterpret_cast<const bf16x8*>(&b_lds[boff[kk] + ni * (16 * 64)]);
      #pragma unroll
      for (int mi = 0; mi < 4; ++mi)
        #pragma unroll
        for (int ni = 0; ni < 4; ++ni)
          acc[mi][ni] = __builtin_amdgcn_mfma_f32_16x16x32_bf16(af[mi], bb[ni], acc[mi][ni], 0, 0, 0);
    }
  }

  #pragma unroll
  for (int ni = 0; ni < 4; ++ni) {
    const int pix = p0 + wcol * 64 + ni * 16 + (lane & 15);
    const int n2  = pix / PIXIMG;
    const int pr2 = pix - n2 * PIXIMG;
    float* ob = out + (size_t)n2 * (CO * PIXIMG) + pr2
                    + (size_t)(co0 + wrow * 64 + ((lane >> 4) * 4)) * PIXIMG;
    #pragma unroll
    for (int mi = 0; mi < 4; ++mi) {
      float* po = ob + (size_t)mi * (16 * PIXIMG);
      #pragma unroll
      for (int r = 0; r < 4; ++r)
        po[(size_t)r * PIXIMG] = acc[mi][ni][r];
    }
  }
}

extern "C" void kernel_launch(void* const* d_in, const int* in_sizes, int n_in,
                              void* d_out, int out_size, void* d_ws, size_t ws_size,
                              hipStream_t stream) {
  const float* x  = (const float*)d_in[0];
  const float* wt = (const float*)d_in[1];
  float* out = (float*)d_out;

  ushort* w2 = (ushort*)d_ws;
  ushort* x2 = (ushort*)((char*)d_ws + 589824);

  const size_t need = 589824 + (size_t)NB * XIMG * 2;   // ~34.1 MB

  if (ws_size >= need) {
    repack_w_kernel<<<dim3(CO), dim3(256), 0, stream>>>(wt, w2);
    repack_x_kernel<<<dim3(HIN, NB), dim3(256), 0, stream>>>(x, x2);
    conv_8ph_kernel<<<dim3(481), dim3(512), 0, stream>>>(x2, w2, out);
  } else {
    conv_fallback_kernel<<<dim3(CO / 128, NPIX / 128), dim3(256), 0, stream>>>(x, wt, out);
  }
}